// Round 1
// baseline (194.969 us; speedup 1.0000x reference)
//
#include <hip/hip_runtime.h>

typedef __attribute__((ext_vector_type(4))) float f32x4;
typedef __attribute__((ext_vector_type(8))) short bf16x8;
typedef __attribute__((ext_vector_type(4))) unsigned int u32x4;
typedef __attribute__((ext_vector_type(4))) unsigned short u16x4;

#define MFMA_BF16(a, b, c) __builtin_amdgcn_mfma_f32_16x16x32_bf16((a), (b), (c), 0, 0, 0)

__device__ __forceinline__ unsigned short f2bf(float f) {
  union { float f; unsigned int u; } v; v.f = f;
  unsigned int u = v.u;
  return (unsigned short)((u + 0x7fffu + ((u >> 16) & 1u)) >> 16);
}
__device__ __forceinline__ float bf2f(unsigned short h) {
  union { unsigned int u; float f; } v; v.u = ((unsigned int)h) << 16;
  return v.f;
}

// ---------- prep: transpose f32 [K][N] -> bf16 hi/lo [N][K] ----------
__global__ __launch_bounds__(256)
void k_prep(const float* __restrict__ in, unsigned short* __restrict__ hi,
            unsigned short* __restrict__ lo, int K, int N) {
  __shared__ float t[64][65];
  const int tid = threadIdx.x;
  const int bn = blockIdx.x * 64, bk = blockIdx.y * 64;
  #pragma unroll
  for (int it = 0; it < 16; ++it) {
    int idx = it * 256 + tid;
    int kk = idx >> 6, nn = idx & 63;
    t[kk][nn] = in[(bk + kk) * N + bn + nn];
  }
  __syncthreads();
  #pragma unroll
  for (int it = 0; it < 16; ++it) {
    int idx = it * 256 + tid;
    int nn = idx >> 6, kk = idx & 63;
    float v = t[kk][nn];
    unsigned short h = f2bf(v);
    int o = (bn + nn) * K + bk + kk;
    hi[o] = h;
    lo[o] = f2bf(v - bf2f(h));
  }
}

// ---------- GEMM1: qkv = x @ w_qkv (hi/lo compensated), fused RoPE epilogue ----------
// grid (12, 64): x = col-tile (N=1536), y = row-tile (M=8192). 256 thr = 4 waves, 128x128 tile.
__global__ __launch_bounds__(256, 2)
void k_gemm_qkv(const float* __restrict__ x,
                const unsigned short* __restrict__ wT_hi,
                const unsigned short* __restrict__ wT_lo,
                const int* __restrict__ pos_h,
                const int* __restrict__ pos_w,
                unsigned short* __restrict__ qh,
                unsigned short* __restrict__ kh,
                unsigned short* __restrict__ vT) {
  __shared__ char As_hi[8192], As_lo[8192], Bs_hi[8192], Bs_lo[8192];
  const int tid = threadIdx.x;
  const int lane = tid & 63, w = tid >> 6;
  const int lr = lane & 15, g = lane >> 4;
  const int m0 = blockIdx.y * 128;
  const int n0 = blockIdx.x * 128;
  const int wr = w >> 1, wc = w & 1;

  f32x4 acc[4][4];
  #pragma unroll
  for (int i = 0; i < 4; ++i)
    #pragma unroll
    for (int j = 0; j < 4; ++j) acc[i][j] = (f32x4){0.f, 0.f, 0.f, 0.f};

  for (int kt = 0; kt < 16; ++kt) {
    const int k0 = kt * 32;
    __syncthreads();
    // stage A (x f32 -> hi/lo bf16), tile 128 rows x 32 k
    #pragma unroll
    for (int it = 0; it < 4; ++it) {
      int idx = it * 256 + tid;
      int r = idx >> 3, c4 = idx & 7;
      f32x4 v = *(const f32x4*)&x[(m0 + r) * 512 + k0 + c4 * 4];
      u16x4 h4, l4;
      #pragma unroll
      for (int e = 0; e < 4; ++e) {
        unsigned short h = f2bf(v[e]);
        h4[e] = h;
        l4[e] = f2bf(v[e] - bf2f(h));
      }
      int a = ((r << 6) + (c4 << 3)) ^ ((r & 7) << 4);
      *(u16x4*)(As_hi + a) = h4;
      *(u16x4*)(As_lo + a) = l4;
    }
    // stage B (wT bf16 hi/lo), tile 128 n-rows x 32 k
    #pragma unroll
    for (int it = 0; it < 2; ++it) {
      int idx = it * 256 + tid;
      int r = idx >> 2, ch = idx & 3;
      int goff = (n0 + r) * 512 + k0 + ch * 8;
      u32x4 h = *(const u32x4*)&wT_hi[goff];
      u32x4 l = *(const u32x4*)&wT_lo[goff];
      int a = ((r << 6) + (ch << 4)) ^ ((r & 7) << 4);
      *(u32x4*)(Bs_hi + a) = h;
      *(u32x4*)(Bs_lo + a) = l;
    }
    __syncthreads();

    bf16x8 ah[4], al[4], bh[4], bl[4];
    #pragma unroll
    for (int mi = 0; mi < 4; ++mi) {
      int r = 64 * wr + 16 * mi + lr;
      int a = ((r << 6) + (g << 4)) ^ ((r & 7) << 4);
      ah[mi] = *(const bf16x8*)(As_hi + a);
      al[mi] = *(const bf16x8*)(As_lo + a);
    }
    #pragma unroll
    for (int nj = 0; nj < 4; ++nj) {
      int r = 64 * wc + 16 * nj + lr;
      int a = ((r << 6) + (g << 4)) ^ ((r & 7) << 4);
      bh[nj] = *(const bf16x8*)(Bs_hi + a);
      bl[nj] = *(const bf16x8*)(Bs_lo + a);
    }
    #pragma unroll
    for (int mi = 0; mi < 4; ++mi)
      #pragma unroll
      for (int nj = 0; nj < 4; ++nj) {
        acc[mi][nj] = MFMA_BF16(ah[mi], bh[nj], acc[mi][nj]);
        acc[mi][nj] = MFMA_BF16(ah[mi], bl[nj], acc[mi][nj]);
        acc[mi][nj] = MFMA_BF16(al[mi], bh[nj], acc[mi][nj]);
      }
  }

  // epilogue: RoPE (q,k) + transpose-write (v)
  #pragma unroll
  for (int mi = 0; mi < 4; ++mi) {
    const int r0f = m0 + 64 * wr + 16 * mi + 4 * g;  // 4 consecutive rows
    const int n = r0f >> 11;
    const int t = r0f & 2047;
    #pragma unroll
    for (int nj = 0; nj < 4; ++nj) {
      const int c = n0 + 64 * wc + 16 * nj + lr;
      const int mat = c >> 9;          // 0=q 1=k 2=v
      const int hh = (c >> 6) & 7;
      const int dh = c & 63;
      f32x4 v = acc[mi][nj];
      if (mat == 2) {
        u16x4 pk;
        #pragma unroll
        for (int e = 0; e < 4; ++e) pk[e] = f2bf(v[e]);
        *(u16x4*)(vT + (size_t)((n * 8 + hh) * 64 + dh) * 2048 + t) = pk;
      } else {
        const int p = (dh & 31) >> 1;
        const float freq = exp2f((float)p * -0.8304820237218405f);  // theta^(-p/16)
        const int odd = lane & 1;
        const int* posArr = (dh < 32) ? pos_h : pos_w;
        unsigned short* dst = mat ? kh : qh;
        const float scale = mat ? 1.0f : 0.125f;  // fold 1/sqrt(64) into q
        #pragma unroll
        for (int i = 0; i < 4; ++i) {
          float val = v[i];
          float oth = __shfl_xor(val, 1);
          float ang = (float)posArr[t + i] * freq;
          float sv, cv;
          __sincosf(ang, &sv, &cv);
          float x1 = odd ? oth : val;
          float x2 = odd ? val : oth;
          float res = odd ? (x1 * sv + x2 * cv) : (x1 * cv - x2 * sv);
          dst[(size_t)((n * 8 + hh) * 2048 + t + i) * 64 + dh] = f2bf(res * scale);
        }
      }
    }
  }
}

// ---------- flash attention: grid (16 qtiles, 32 nh), 256 thr, QT=128, KT=128 ----------
__global__ __launch_bounds__(256, 2)
void k_attn(const unsigned short* __restrict__ qh,
            const unsigned short* __restrict__ kh,
            const unsigned short* __restrict__ vT,
            unsigned short* __restrict__ o_flat) {
  __shared__ char Ks[16384];   // [128 s][64 dh] bf16, swz ^((s&7)<<4)
  __shared__ char Vs[16384];   // [64 dh][128 s] bf16 (V^T), swz ^((dh&7)<<4)
  __shared__ char Ps[32768];   // per-wave 8KB: [32 q][128 s] bf16, swz ^((q&7)<<4)
  const int tid = threadIdx.x, lane = tid & 63, w = tid >> 6;
  const int lr = lane & 15, g = lane >> 4;
  const int qt = blockIdx.x, nh = blockIdx.y;

  // Q fragments straight from global (A-layout): row=lr, k=8g+e
  bf16x8 qf[2][2];
  const unsigned short* qbase = qh + (nh * 2048 + qt * 128 + w * 32) * 64;
  #pragma unroll
  for (int mi = 0; mi < 2; ++mi)
    #pragma unroll
    for (int kg = 0; kg < 2; ++kg)
      qf[mi][kg] = *(const bf16x8*)(qbase + (16 * mi + lr) * 64 + kg * 32 + g * 8);

  f32x4 oacc[2][4];
  float m_run[2][4], l_run[2][4];
  #pragma unroll
  for (int mi = 0; mi < 2; ++mi) {
    #pragma unroll
    for (int nf = 0; nf < 4; ++nf) oacc[mi][nf] = (f32x4){0.f, 0.f, 0.f, 0.f};
    #pragma unroll
    for (int i = 0; i < 4; ++i) { m_run[mi][i] = -3.0e38f; l_run[mi][i] = 0.f; }
  }

  const unsigned short* kb = kh + nh * 2048 * 64;
  const unsigned short* vb = vT + nh * 64 * 2048;

  for (int kt = 0; kt < 16; ++kt) {
    __syncthreads();
    #pragma unroll
    for (int it = 0; it < 4; ++it) {           // stage K tile 128x(128B)
      int idx = it * 256 + tid;
      int s = idx >> 3, ch = idx & 7;
      u32x4 d = *(const u32x4*)(kb + (kt * 128 + s) * 64 + ch * 8);
      int a = ((s << 7) + (ch << 4)) ^ ((s & 7) << 4);
      *(u32x4*)(Ks + a) = d;
    }
    #pragma unroll
    for (int it = 0; it < 4; ++it) {           // stage V^T tile 64x(256B)
      int idx = it * 256 + tid;
      int dh = idx >> 4, ch = idx & 15;
      u32x4 d = *(const u32x4*)(vb + dh * 2048 + kt * 128 + ch * 8);
      int a = ((dh << 8) + (ch << 4)) ^ ((dh & 7) << 4);
      *(u32x4*)(Vs + a) = d;
    }
    __syncthreads();

    // S = Q K^T  (A=Q, B=K^T: lane col = K-row s)
    f32x4 sacc[2][8];
    #pragma unroll
    for (int mi = 0; mi < 2; ++mi)
      #pragma unroll
      for (int sj = 0; sj < 8; ++sj) sacc[mi][sj] = (f32x4){0.f, 0.f, 0.f, 0.f};
    #pragma unroll
    for (int sj = 0; sj < 8; ++sj) {
      int s = sj * 16 + lr;
      #pragma unroll
      for (int kg = 0; kg < 2; ++kg) {
        int a = ((s << 7) + (kg << 6) + (g << 4)) ^ ((s & 7) << 4);
        bf16x8 kf = *(const bf16x8*)(Ks + a);
        #pragma unroll
        for (int mi = 0; mi < 2; ++mi)
          sacc[mi][sj] = MFMA_BF16(qf[mi][kg], kf, sacc[mi][sj]);
      }
    }

    // online softmax (rows live on 16-lane groups; reduce via shfl_xor 1,2,4,8)
    #pragma unroll
    for (int mi = 0; mi < 2; ++mi) {
      #pragma unroll
      for (int i = 0; i < 4; ++i) {
        float mx = sacc[mi][0][i];
        #pragma unroll
        for (int sj = 1; sj < 8; ++sj) mx = fmaxf(mx, sacc[mi][sj][i]);
        #pragma unroll
        for (int d = 1; d < 16; d <<= 1) mx = fmaxf(mx, __shfl_xor(mx, d));
        float nm = fmaxf(m_run[mi][i], mx);
        float corr = __expf(m_run[mi][i] - nm);
        m_run[mi][i] = nm;
        float rs = 0.f;
        #pragma unroll
        for (int sj = 0; sj < 8; ++sj) {
          float pv = __expf(sacc[mi][sj][i] - nm);
          sacc[mi][sj][i] = pv;
          rs += pv;
        }
        #pragma unroll
        for (int d = 1; d < 16; d <<= 1) rs += __shfl_xor(rs, d);
        l_run[mi][i] = l_run[mi][i] * corr + rs;
        #pragma unroll
        for (int nf = 0; nf < 4; ++nf) oacc[mi][nf][i] *= corr;
        // store P row to per-wave LDS (D-layout -> [q][s])
        int q = 16 * mi + 4 * g + i;
        #pragma unroll
        for (int sj = 0; sj < 8; ++sj) {
          int a = (w * 8192 + (q << 8) + (sj << 5) + (lr << 1)) ^ ((q & 7) << 4);
          *(unsigned short*)(Ps + a) = f2bf(sacc[mi][sj][i]);
        }
      }
    }

    // O += P V   (A=P from LDS, B=V from V^T LDS)
    #pragma unroll
    for (int ks = 0; ks < 4; ++ks) {
      bf16x8 pf[2];
      #pragma unroll
      for (int mi = 0; mi < 2; ++mi) {
        int q = 16 * mi + lr;
        int a = (w * 8192 + (q << 8) + (ks << 6) + (g << 4)) ^ ((q & 7) << 4);
        pf[mi] = *(const bf16x8*)(Ps + a);
      }
      #pragma unroll
      for (int nf = 0; nf < 4; ++nf) {
        int dh = nf * 16 + lr;
        int a = ((dh << 8) + (ks << 6) + (g << 4)) ^ ((dh & 7) << 4);
        bf16x8 vf = *(const bf16x8*)(Vs + a);
        #pragma unroll
        for (int mi = 0; mi < 2; ++mi)
          oacc[mi][nf] = MFMA_BF16(pf[mi], vf, oacc[mi][nf]);
      }
    }
  }

  // epilogue: o = oacc / l, write bf16 [8192][512]
  const int n = nh >> 3, h = nh & 7;
  #pragma unroll
  for (int mi = 0; mi < 2; ++mi)
    #pragma unroll
    for (int i = 0; i < 4; ++i) {
      float inv = 1.0f / l_run[mi][i];
      int row = qt * 128 + w * 32 + 16 * mi + 4 * g + i;
      #pragma unroll
      for (int nf = 0; nf < 4; ++nf)
        o_flat[(n * 2048 + row) * 512 + h * 64 + nf * 16 + lr] =
            f2bf(oacc[mi][nf][i] * inv);
    }
}

// ---------- GEMM3: out = o_flat @ w_proj + b  (plain bf16) ----------
// grid (4, 64), 128x128 tile, 256 thr
__global__ __launch_bounds__(256, 2)
void k_gemm_proj(const unsigned short* __restrict__ o_flat,
                 const unsigned short* __restrict__ wpT,
                 const float* __restrict__ bias,
                 float* __restrict__ out) {
  __shared__ char As[8192], Bs[8192];
  const int tid = threadIdx.x;
  const int lane = tid & 63, w = tid >> 6;
  const int lr = lane & 15, g = lane >> 4;
  const int m0 = blockIdx.y * 128;
  const int n0 = blockIdx.x * 128;
  const int wr = w >> 1, wc = w & 1;

  f32x4 acc[4][4];
  #pragma unroll
  for (int i = 0; i < 4; ++i)
    #pragma unroll
    for (int j = 0; j < 4; ++j) acc[i][j] = (f32x4){0.f, 0.f, 0.f, 0.f};

  for (int kt = 0; kt < 16; ++kt) {
    const int k0 = kt * 32;
    __syncthreads();
    #pragma unroll
    for (int it = 0; it < 2; ++it) {
      int idx = it * 256 + tid;
      int r = idx >> 2, ch = idx & 3;
      u32x4 d = *(const u32x4*)&o_flat[(m0 + r) * 512 + k0 + ch * 8];
      int a = ((r << 6) + (ch << 4)) ^ ((r & 7) << 4);
      *(u32x4*)(As + a) = d;
    }
    #pragma unroll
    for (int it = 0; it < 2; ++it) {
      int idx = it * 256 + tid;
      int r = idx >> 2, ch = idx & 3;
      u32x4 d = *(const u32x4*)&wpT[(n0 + r) * 512 + k0 + ch * 8];
      int a = ((r << 6) + (ch << 4)) ^ ((r & 7) << 4);
      *(u32x4*)(Bs + a) = d;
    }
    __syncthreads();

    bf16x8 af[4], bf[4];
    #pragma unroll
    for (int mi = 0; mi < 4; ++mi) {
      int r = 64 * wr + 16 * mi + lr;
      int a = ((r << 6) + (g << 4)) ^ ((r & 7) << 4);
      af[mi] = *(const bf16x8*)(As + a);
    }
    #pragma unroll
    for (int nj = 0; nj < 4; ++nj) {
      int r = 64 * wc + 16 * nj + lr;
      int a = ((r << 6) + (g << 4)) ^ ((r & 7) << 4);
      bf[nj] = *(const bf16x8*)(Bs + a);
    }
    #pragma unroll
    for (int mi = 0; mi < 4; ++mi)
      #pragma unroll
      for (int nj = 0; nj < 4; ++nj)
        acc[mi][nj] = MFMA_BF16(af[mi], bf[nj], acc[mi][nj]);
  }

  #pragma unroll
  for (int mi = 0; mi < 4; ++mi) {
    int r0f = m0 + 64 * wr + 16 * mi + 4 * g;
    #pragma unroll
    for (int nj = 0; nj < 4; ++nj) {
      int c = n0 + 64 * wc + 16 * nj + lr;
      float b = bias[c];
      #pragma unroll
      for (int i = 0; i < 4; ++i)
        out[(size_t)(r0f + i) * 512 + c] = acc[mi][nj][i] + b;
    }
  }
}

extern "C" void kernel_launch(void* const* d_in, const int* in_sizes, int n_in,
                              void* d_out, int out_size, void* d_ws, size_t ws_size,
                              hipStream_t stream) {
  const float* x      = (const float*)d_in[0];
  const int*   pos_h  = (const int*)d_in[1];
  const int*   pos_w  = (const int*)d_in[2];
  const float* w_qkv  = (const float*)d_in[3];
  const float* w_proj = (const float*)d_in[4];
  const float* b_proj = (const float*)d_in[5];
  float* out = (float*)d_out;

  char* ws = (char*)d_ws;
  size_t off = 0;
  auto alloc = [&](size_t bytes) {
    char* p = ws + off;
    off += (bytes + 1023) & ~(size_t)1023;
    return p;
  };
  unsigned short* qh     = (unsigned short*)alloc((size_t)32 * 2048 * 64 * 2);
  unsigned short* kh     = (unsigned short*)alloc((size_t)32 * 2048 * 64 * 2);
  unsigned short* vT     = (unsigned short*)alloc((size_t)32 * 2048 * 64 * 2);
  unsigned short* o_flat = (unsigned short*)alloc((size_t)8192 * 512 * 2);
  unsigned short* wqT_hi = (unsigned short*)alloc((size_t)1536 * 512 * 2);
  unsigned short* wqT_lo = (unsigned short*)alloc((size_t)1536 * 512 * 2);
  unsigned short* wpT_hi = (unsigned short*)alloc((size_t)512 * 512 * 2);
  unsigned short* wpT_lo = (unsigned short*)alloc((size_t)512 * 512 * 2);

  hipLaunchKernelGGL(k_prep, dim3(24, 8), dim3(256), 0, stream, w_qkv, wqT_hi, wqT_lo, 512, 1536);
  hipLaunchKernelGGL(k_prep, dim3(8, 8), dim3(256), 0, stream, w_proj, wpT_hi, wpT_lo, 512, 512);
  hipLaunchKernelGGL(k_gemm_qkv, dim3(12, 64), dim3(256), 0, stream,
                     x, wqT_hi, wqT_lo, pos_h, pos_w, qh, kh, vT);
  hipLaunchKernelGGL(k_attn, dim3(16, 32), dim3(256), 0, stream, qh, kh, vT, o_flat);
  hipLaunchKernelGGL(k_gemm_proj, dim3(4, 64), dim3(256), 0, stream, o_flat, wpT_hi, b_proj, out);
}